// Round 1
// baseline (361.899 us; speedup 1.0000x reference)
//
#include <hip/hip_runtime.h>
#include <math.h>

// Problem constants (from reference setup_inputs)
constexpr int B = 2, S = 5, C = 256, H = 200, W = 200;
constexpr int KW = 7;              // window
constexpr int HB = 29, WB = 29;    // padded 203/7
constexpr int HID = 16;
constexpr int WPAD = 203;          // padded width

// ---------------------------------------------------------------------------
// Kernel 1: per-window channel sums.
// One block (64 threads) per (b,s,c,hb). Stage 7 rows (padded with zeros)
// into LDS coalesced, then lanes 0..28 compute the 29 window sums.
// gsum layout: [B,S,HB,WB,C]  (C contiguous, for kernel 2's per-lane dot)
// ---------------------------------------------------------------------------
__global__ __launch_bounds__(64) void k_winsum(const float* __restrict__ feats,
                                               float* __restrict__ gsum) {
    int blk = blockIdx.x;
    int hb = blk % HB; blk /= HB;
    int c  = blk % C;  blk /= C;
    int s  = blk % S;
    int b  = blk / S;

    __shared__ float rows[KW][204];

    const float* src = feats + ((size_t)((b * S + s) * C + c)) * H * W;
    int y0 = hb * KW;
    for (int i = 0; i < KW; ++i) {
        int y = y0 + i;
        for (int x = (int)threadIdx.x; x < WPAD; x += 64) {
            rows[i][x] = (y < H && x < W) ? src[(size_t)y * W + x] : 0.0f;
        }
    }
    __syncthreads();

    int wb = threadIdx.x;
    if (wb < WB) {
        float sum = 0.0f;
#pragma unroll
        for (int i = 0; i < KW; ++i) {
#pragma unroll
            for (int j = 0; j < KW; ++j) {
                sum += rows[i][wb * KW + j];
            }
        }
        size_t gi = ((size_t)((b * S + s) * HB + hb) * WB + wb) * C + c;
        gsum[gi] = sum;
    }
}

// ---------------------------------------------------------------------------
// Kernel 2: MLP + softmax over wb.
// One block (64 threads) per (b,s,hb). Lane wb (<29) computes
// logit = w2 . relu(w1 . (gsum/49) + b1) + b2, then softmax across the 29
// lanes of this row via a small LDS array.
// ---------------------------------------------------------------------------
__global__ __launch_bounds__(64) void k_weights(const float* __restrict__ gsum,
                                                const float* __restrict__ w1,
                                                const float* __restrict__ b1,
                                                const float* __restrict__ w2,
                                                const float* __restrict__ b2,
                                                float* __restrict__ weights) {
    int blk = blockIdx.x;
    int hb = blk % HB; blk /= HB;
    int s  = blk % S;
    int b  = blk / S;

    __shared__ float w1s[HID * C];   // 16 KB
    __shared__ float lg[WB];

    for (int i = (int)threadIdx.x; i < HID * C; i += 64) w1s[i] = w1[i];
    __syncthreads();

    int wb = threadIdx.x;
    if (wb < WB) {
        const float* g = gsum + ((size_t)((b * S + s) * HB + hb) * WB + wb) * C;
        float logit = b2[0];
#pragma unroll
        for (int d = 0; d < HID; ++d) {
            float acc = 0.0f;
            for (int c = 0; c < C; ++c) acc += g[c] * w1s[d * C + c];
            float h = acc * (1.0f / 49.0f) + b1[d];
            h = h > 0.0f ? h : 0.0f;
            logit += h * w2[d];
        }
        lg[wb] = logit;
    }
    __syncthreads();

    if (wb < WB) {
        float m = -INFINITY;
        for (int t = 0; t < WB; ++t) m = fmaxf(m, lg[t]);
        float sum = 0.0f;
        for (int t = 0; t < WB; ++t) sum += expf(lg[t] - m);
        weights[(size_t)((b * S + s) * HB + hb) * WB + wb] = expf(lg[wb] - m) / sum;
    }
}

// ---------------------------------------------------------------------------
// Kernel 3: weighted fusion + faithful reassembly.
// One block (256 threads) per (b,c). Stage weights[b,:,:,:] (4205 floats) in
// LDS, then grid-stride over the 200x200 output plane.
// out[b,c, i*29+hb, j*29+wb] = sum_s feats_pad[b,s,c, hb*7+i, wb*7+j] * w[s,hb,wb]
// ---------------------------------------------------------------------------
__global__ __launch_bounds__(256) void k_fuse(const float* __restrict__ feats,
                                              const float* __restrict__ weights,
                                              float* __restrict__ out) {
    int c = blockIdx.x % C;
    int b = blockIdx.x / C;

    __shared__ float ws[S * HB * WB];   // 4205 floats = 16.8 KB
    for (int i = (int)threadIdx.x; i < S * HB * WB; i += 256)
        ws[i] = weights[(size_t)b * S * HB * WB + i];
    __syncthreads();

    const float* f0 = feats + ((size_t)b * S * C + c) * H * W;  // slice stride C*H*W
    float* o = out + ((size_t)b * C + c) * H * W;
    const size_t sstride = (size_t)C * H * W;

    for (int idx = (int)threadIdx.x; idx < H * W; idx += 256) {
        int y = idx / W;
        int x = idx - y * W;
        int i  = y / HB;           // 0..6
        int hb = y - i * HB;       // 0..28
        int j  = x / WB;           // 0..6
        int wb = x - j * WB;       // 0..28
        int y_in = hb * KW + i;
        int x_in = wb * KW + j;

        float acc = 0.0f;
        if (y_in < H && x_in < W) {
            size_t off = (size_t)y_in * W + x_in;
            int widx = hb * WB + wb;
#pragma unroll
            for (int s = 0; s < S; ++s) {
                acc += f0[(size_t)s * sstride + off] * ws[s * HB * WB + widx];
            }
        }
        o[idx] = acc;
    }
}

// ---------------------------------------------------------------------------
extern "C" void kernel_launch(void* const* d_in, const int* in_sizes, int n_in,
                              void* d_out, int out_size, void* d_ws, size_t ws_size,
                              hipStream_t stream) {
    const float* feats = (const float*)d_in[0];
    const float* w1    = (const float*)d_in[1];
    const float* b1    = (const float*)d_in[2];
    const float* w2    = (const float*)d_in[3];
    const float* b2    = (const float*)d_in[4];
    float* out = (float*)d_out;

    // Workspace layout
    float* gsum    = (float*)d_ws;                         // B*S*HB*WB*C = 2,152,960 floats
    float* weights = gsum + (size_t)B * S * HB * WB * C;   // B*S*HB*WB   = 8,410 floats

    // Kernel 1: window sums
    {
        int nblk = B * S * C * HB;   // 74,240
        hipLaunchKernelGGL(k_winsum, dim3(nblk), dim3(64), 0, stream, feats, gsum);
    }
    // Kernel 2: MLP + softmax -> weights
    {
        int nblk = B * S * HB;       // 290
        hipLaunchKernelGGL(k_weights, dim3(nblk), dim3(64), 0, stream,
                           gsum, w1, b1, w2, b2, weights);
    }
    // Kernel 3: weighted fusion
    {
        int nblk = B * C;            // 512
        hipLaunchKernelGGL(k_fuse, dim3(nblk), dim3(256), 0, stream,
                           feats, weights, out);
    }
}

// Round 2
// 247.179 us; speedup vs baseline: 1.4641x; 1.4641x over previous
//
#include <hip/hip_runtime.h>
#include <math.h>

// Problem constants (from reference setup_inputs)
constexpr int B = 2, S = 5, C = 256, H = 200, W = 200;
constexpr int KW = 7;              // window
constexpr int HB = 29, WB = 29;    // ceil(203/7)
constexpr int HID = 16;
constexpr int NW = HB * WB;        // 841

// ---------------------------------------------------------------------------
// Kernel 1: per-window channel sums, one 256-thread block per (b,s,c) plane.
// Streams the contiguous 160 KB plane with float4 loads, separable 7x7 sums
// via LDS (column-group sums then row sums).
// gsum layout: [B*S*C][841]  (contiguous writes here; coalesced reads in k2)
// ---------------------------------------------------------------------------
__global__ __launch_bounds__(256) void k_winsum(const float* __restrict__ feats,
                                                float* __restrict__ gsum) {
    const int blk = blockIdx.x;                 // (b*S+s)*C + c
    const float* src = feats + (size_t)blk * (H * W);
    float* dst = gsum + (size_t)blk * NW;

    __shared__ float rows[KW * W];              // 7*200 floats = 5.6 KB
    __shared__ float cs[KW * WB];               // 203 floats

    const int tid = (int)threadIdx.x;

    for (int hb = 0; hb < HB; ++hb) {
        // stage 7 rows (y = hb*7 + i) as float4, zero rows past H
        for (int q = tid; q < KW * (W / 4); q += 256) {   // 350 float4
            int i  = q / (W / 4);
            int xq = q - i * (W / 4);
            int y  = hb * KW + i;
            float4 v = make_float4(0.f, 0.f, 0.f, 0.f);
            if (y < H) v = ((const float4*)(src + (size_t)y * W))[xq];
            ((float4*)rows)[i * (W / 4) + xq] = v;
        }
        __syncthreads();
        // column-group sums: cs[i*WB+wb] = sum_j rows[i*W + wb*7+j], x<W
        for (int p = tid; p < KW * WB; p += 256) {        // 203 items
            int i  = p / WB;
            int wb = p - i * WB;
            float s = 0.f;
            int x0 = wb * KW;
#pragma unroll
            for (int j = 0; j < KW; ++j) {
                int x = x0 + j;
                if (x < W) s += rows[i * W + x];
            }
            cs[p] = s;
        }
        __syncthreads();
        // 7-row sums -> 29 window sums, contiguous store
        if (tid < WB) {
            float s = 0.f;
#pragma unroll
            for (int i = 0; i < KW; ++i) s += cs[i * WB + tid];
            dst[hb * WB + tid] = s;
        }
        __syncthreads();
    }
}

// ---------------------------------------------------------------------------
// Kernel 2: MLP + softmax over wb. One 64-thread block per (b,s,hb).
// Lane wb computes logit = w2 . relu(w1 . (gsum/49) + b1) + b2, softmax over
// the 29 lanes via LDS. Reads gsum[(bs*C+c)*841 + hb*29 + wb] -> 29
// consecutive floats per wave per c (coalesced).
// ---------------------------------------------------------------------------
__global__ __launch_bounds__(64) void k_weights(const float* __restrict__ gsum,
                                                const float* __restrict__ w1,
                                                const float* __restrict__ b1,
                                                const float* __restrict__ w2,
                                                const float* __restrict__ b2,
                                                float* __restrict__ weights) {
    int blk = blockIdx.x;
    int hb = blk % HB; blk /= HB;
    int s  = blk % S;
    int b  = blk / S;
    const int bs = b * S + s;

    __shared__ float w1s[HID * C];   // 16 KB
    __shared__ float lg[WB];

    for (int i = (int)threadIdx.x; i < HID * C; i += 64) w1s[i] = w1[i];
    __syncthreads();

    const int wb = (int)threadIdx.x;
    if (wb < WB) {
        float acc[HID];
#pragma unroll
        for (int d = 0; d < HID; ++d) acc[d] = 0.f;
        const float* g = gsum + (size_t)bs * C * NW + hb * WB + wb;
        for (int c = 0; c < C; ++c) {
            float gc = g[(size_t)c * NW];
#pragma unroll
            for (int d = 0; d < HID; ++d) acc[d] += gc * w1s[d * C + c];
        }
        float logit = b2[0];
#pragma unroll
        for (int d = 0; d < HID; ++d) {
            float h = acc[d] * (1.0f / 49.0f) + b1[d];
            logit += fmaxf(h, 0.0f) * w2[d];
        }
        lg[wb] = logit;
    }
    __syncthreads();
    if (wb < WB) {
        float m = -INFINITY;
        for (int t = 0; t < WB; ++t) m = fmaxf(m, lg[t]);
        float sum = 0.f;
        for (int t = 0; t < WB; ++t) sum += expf(lg[t] - m);
        weights[(size_t)bs * NW + hb * WB + wb] = expf(lg[wb] - m) / sum;
    }
}

// ---------------------------------------------------------------------------
// Kernel 3: weighted fusion. Key fact: output row y = i*29+hb needs exactly
// one input row y_in = hb*7+i (per slice). Block = (b, c, group of 4 output
// rows). Stage 5 slices x 4 input rows into LDS (coalesced float4), permute
// columns via LDS gather (x_in = (x%29)*7 + x/29, stride-7 -> <=2-way bank
// aliasing = free), write output rows coalesced.
// ---------------------------------------------------------------------------
constexpr int RPB = 4;  // output rows per block
__global__ __launch_bounds__(256) void k_fuse(const float* __restrict__ feats,
                                              const float* __restrict__ weights,
                                              float* __restrict__ out) {
    int blk = blockIdx.x;
    const int g = blk % (H / RPB); blk /= (H / RPB);
    const int c = blk % C;
    const int b = blk / C;
    const int y0 = g * RPB;

    __shared__ float buf[S][RPB][W];     // 16 KB
    __shared__ float wsl[S][RPB][WB];    // 2.3 KB

    const int tid = (int)threadIdx.x;
    const size_t plane = (size_t)H * W;
    const size_t sstride = (size_t)C * plane;
    const float* f0 = feats + ((size_t)b * S * C + c) * plane;

    // stage input rows (float4, coalesced); zero the padded rows
    for (int q = tid; q < S * RPB * (W / 4); q += 256) {  // 1000 float4
        int s  = q / (RPB * (W / 4));
        int r  = q - s * (RPB * (W / 4));
        int yy = r / (W / 4);
        int xq = r - yy * (W / 4);
        int y  = y0 + yy;
        int i  = y / HB;
        int hb = y - i * HB;
        int y_in = hb * KW + i;
        float4 v = make_float4(0.f, 0.f, 0.f, 0.f);
        if (y_in < H)
            v = ((const float4*)(f0 + (size_t)s * sstride + (size_t)y_in * W))[xq];
        ((float4*)&buf[s][yy][0])[xq] = v;
    }
    // stage the needed weight rows
    for (int q = tid; q < S * RPB * WB; q += 256) {       // 580 floats
        int s  = q / (RPB * WB);
        int r  = q - s * (RPB * WB);
        int yy = r / WB;
        int wb = r - yy * WB;
        int hb = (y0 + yy) % HB;
        wsl[s][yy][wb] = weights[((size_t)(b * S + s) * HB + hb) * WB + wb];
    }
    __syncthreads();

    float* o = out + ((size_t)b * C + c) * plane + (size_t)y0 * W;
    for (int p = tid; p < RPB * W; p += 256) {            // 800 outputs
        int yy = p / W;
        int x  = p - yy * W;
        int j  = x / WB;
        int wb = x - j * WB;
        int x_in = wb * KW + j;
        float acc = 0.f;
        if (x_in < W) {
#pragma unroll
            for (int s = 0; s < S; ++s)
                acc += buf[s][yy][x_in] * wsl[s][yy][wb];
        }
        o[p] = acc;
    }
}

// ---------------------------------------------------------------------------
extern "C" void kernel_launch(void* const* d_in, const int* in_sizes, int n_in,
                              void* d_out, int out_size, void* d_ws, size_t ws_size,
                              hipStream_t stream) {
    const float* feats = (const float*)d_in[0];
    const float* w1    = (const float*)d_in[1];
    const float* b1    = (const float*)d_in[2];
    const float* w2    = (const float*)d_in[3];
    const float* b2    = (const float*)d_in[4];
    float* out = (float*)d_out;

    // Workspace layout
    float* gsum    = (float*)d_ws;                      // B*S*C*841 = 2,152,960 floats
    float* weights = gsum + (size_t)B * S * C * NW;     // B*S*841   = 8,410 floats

    // Kernel 1: window sums (one block per plane)
    hipLaunchKernelGGL(k_winsum, dim3(B * S * C), dim3(256), 0, stream, feats, gsum);
    // Kernel 2: MLP + softmax -> weights
    hipLaunchKernelGGL(k_weights, dim3(B * S * HB), dim3(64), 0, stream,
                       gsum, w1, b1, w2, b2, weights);
    // Kernel 3: weighted fusion (b, c, row-group)
    hipLaunchKernelGGL(k_fuse, dim3(B * C * (H / RPB)), dim3(256), 0, stream,
                       feats, weights, out);
}

// Round 3
// 194.850 us; speedup vs baseline: 1.8573x; 1.2686x over previous
//
#include <hip/hip_runtime.h>
#include <math.h>

// Problem constants (from reference setup_inputs)
constexpr int B = 2, S = 5, C = 256, H = 200, W = 200;
constexpr int KW = 7;              // window
constexpr int HB = 29, WB = 29;    // ceil(203/7)
constexpr int HID = 16;
constexpr int NW = HB * WB;        // 841

// ---------------------------------------------------------------------------
// Kernel 1: per-window channel sums, one 256-thread block per (b,s,c) plane.
// Phase A: thread owns (hb, x4): 7 vertically-adjacent float4 loads (each
// load is fully coalesced across lanes), sums into LDS colgroup[29][200].
// ONE barrier. Phase B: horizontal 7-window sums -> gsum (contiguous).
// 40 independent float4 loads/thread -> deep vmcnt pipeline, no per-iter
// barrier drain.
// gsum layout: [B*S*C][841]
// ---------------------------------------------------------------------------
__global__ __launch_bounds__(256) void k_winsum(const float* __restrict__ feats,
                                                float* __restrict__ gsum) {
    const int blk = blockIdx.x;                 // (b*S+s)*C + c
    const float* src = feats + (size_t)blk * (H * W);

    __shared__ float colg[HB * W];              // 29*200 floats = 23.2 KB

    const int tid = (int)threadIdx.x;

    // Phase A: 29*50 = 1450 items
    for (int q = tid; q < HB * (W / 4); q += 256) {
        int hb = q / (W / 4);
        int x4 = q - hb * (W / 4);
        int y0 = hb * KW;
        float4 a = make_float4(0.f, 0.f, 0.f, 0.f);
#pragma unroll
        for (int i = 0; i < KW; ++i) {
            int y = y0 + i;
            if (y < H) {
                float4 v = ((const float4*)(src + (size_t)y * W))[x4];
                a.x += v.x; a.y += v.y; a.z += v.z; a.w += v.w;
            }
        }
        ((float4*)(colg + hb * W))[x4] = a;
    }
    __syncthreads();

    // Phase B: 841 horizontal window sums, contiguous store
    float* dst = gsum + (size_t)blk * NW;
    for (int p = tid; p < NW; p += 256) {
        int hb = p / WB;
        int wb = p - hb * WB;
        int x0 = wb * KW;
        float s = 0.f;
#pragma unroll
        for (int j = 0; j < KW; ++j) {
            int x = x0 + j;
            if (x < W) s += colg[hb * W + x];
        }
        dst[p] = s;
    }
}

// ---------------------------------------------------------------------------
// Kernel 2: MLP + softmax over wb. One 256-thread block per (b,s,hb).
// Thread (cg, wb), cg=0..7: partial acc[16] over 32 channels; LDS reduce
// over cg; first wave computes logits + softmax over the 29 wb.
// ---------------------------------------------------------------------------
__global__ __launch_bounds__(256) void k_weights(const float* __restrict__ gsum,
                                                 const float* __restrict__ w1,
                                                 const float* __restrict__ b1,
                                                 const float* __restrict__ w2,
                                                 const float* __restrict__ b2,
                                                 float* __restrict__ weights) {
    int blk = blockIdx.x;
    int hb = blk % HB; blk /= HB;
    int s  = blk % S;
    int b  = blk / S;
    const int bs = b * S + s;

    __shared__ float w1s[HID * C];        // 16 KB
    __shared__ float part[8 * HID * WB];  // 8*16*29 floats = 14.5 KB
    __shared__ float lg[WB];

    const int tid = (int)threadIdx.x;
    for (int i = tid; i < HID * C; i += 256) w1s[i] = w1[i];
    __syncthreads();

    if (tid < 8 * WB) {                   // 232 active
        const int cg = tid / WB;          // 0..7
        const int wb = tid - cg * WB;     // 0..28
        float acc[HID];
#pragma unroll
        for (int d = 0; d < HID; ++d) acc[d] = 0.f;
        const float* g = gsum + (size_t)bs * C * NW + hb * WB + wb;
        const int c0 = cg * (C / 8);
        for (int c = c0; c < c0 + C / 8; ++c) {
            float gc = g[(size_t)c * NW];
#pragma unroll
            for (int d = 0; d < HID; ++d) acc[d] += gc * w1s[d * C + c];
        }
        // transposed store: part[(cg*HID+d)*WB + wb]  (scalar, conflict-free)
#pragma unroll
        for (int d = 0; d < HID; ++d) part[(cg * HID + d) * WB + wb] = acc[d];
    }
    __syncthreads();

    if (tid < WB) {
        float logit = b2[0];
#pragma unroll
        for (int d = 0; d < HID; ++d) {
            float a = 0.f;
#pragma unroll
            for (int cg = 0; cg < 8; ++cg) a += part[(cg * HID + d) * WB + tid];
            float h = a * (1.0f / 49.0f) + b1[d];
            logit += fmaxf(h, 0.0f) * w2[d];
        }
        lg[tid] = logit;
    }
    __syncthreads();
    if (tid < WB) {
        float m = -INFINITY;
        for (int t = 0; t < WB; ++t) m = fmaxf(m, lg[t]);
        float sum = 0.f;
        for (int t = 0; t < WB; ++t) sum += expf(lg[t] - m);
        weights[(size_t)bs * NW + hb * WB + tid] = expf(lg[tid] - m) / sum;
    }
}

// ---------------------------------------------------------------------------
// Kernel 3: weighted fusion. Output row y = i*29+hb needs exactly one input
// row y_in = hb*7+i per slice. Block = (b, c, group of 4 output rows).
// Stage 5 slices x 4 input rows into LDS (coalesced float4), permute columns
// via LDS gather (x_in = (x%29)*7 + x/29, stride-7 -> conflict-free), write
// output rows coalesced.
// ---------------------------------------------------------------------------
constexpr int RPB = 4;  // output rows per block
__global__ __launch_bounds__(256) void k_fuse(const float* __restrict__ feats,
                                              const float* __restrict__ weights,
                                              float* __restrict__ out) {
    int blk = blockIdx.x;
    const int g = blk % (H / RPB); blk /= (H / RPB);
    const int c = blk % C;
    const int b = blk / C;
    const int y0 = g * RPB;

    __shared__ float buf[S][RPB][W];     // 16 KB
    __shared__ float wsl[S][RPB][WB];    // 2.3 KB

    const int tid = (int)threadIdx.x;
    const size_t plane = (size_t)H * W;
    const size_t sstride = (size_t)C * plane;
    const float* f0 = feats + ((size_t)b * S * C + c) * plane;

    // stage input rows (float4, coalesced); zero the padded rows
    for (int q = tid; q < S * RPB * (W / 4); q += 256) {  // 1000 float4
        int s  = q / (RPB * (W / 4));
        int r  = q - s * (RPB * (W / 4));
        int yy = r / (W / 4);
        int xq = r - yy * (W / 4);
        int y  = y0 + yy;
        int i  = y / HB;
        int hb = y - i * HB;
        int y_in = hb * KW + i;
        float4 v = make_float4(0.f, 0.f, 0.f, 0.f);
        if (y_in < H)
            v = ((const float4*)(f0 + (size_t)s * sstride + (size_t)y_in * W))[xq];
        ((float4*)&buf[s][yy][0])[xq] = v;
    }
    // stage the needed weight rows
    for (int q = tid; q < S * RPB * WB; q += 256) {       // 580 floats
        int s  = q / (RPB * WB);
        int r  = q - s * (RPB * WB);
        int yy = r / WB;
        int wb = r - yy * WB;
        int hb = (y0 + yy) % HB;
        wsl[s][yy][wb] = weights[((size_t)(b * S + s) * HB + hb) * WB + wb];
    }
    __syncthreads();

    float* o = out + ((size_t)b * C + c) * plane + (size_t)y0 * W;
    for (int p = tid; p < RPB * W; p += 256) {            // 800 outputs
        int yy = p / W;
        int x  = p - yy * W;
        int j  = x / WB;
        int wb = x - j * WB;
        int x_in = wb * KW + j;
        float acc = 0.f;
        if (x_in < W) {
#pragma unroll
            for (int s = 0; s < S; ++s)
                acc += buf[s][yy][x_in] * wsl[s][yy][wb];
        }
        o[p] = acc;
    }
}

// ---------------------------------------------------------------------------
extern "C" void kernel_launch(void* const* d_in, const int* in_sizes, int n_in,
                              void* d_out, int out_size, void* d_ws, size_t ws_size,
                              hipStream_t stream) {
    const float* feats = (const float*)d_in[0];
    const float* w1    = (const float*)d_in[1];
    const float* b1    = (const float*)d_in[2];
    const float* w2    = (const float*)d_in[3];
    const float* b2    = (const float*)d_in[4];
    float* out = (float*)d_out;

    // Workspace layout
    float* gsum    = (float*)d_ws;                      // B*S*C*841 = 2,152,960 floats
    float* weights = gsum + (size_t)B * S * C * NW;     // B*S*841   = 8,410 floats

    // Kernel 1: window sums (one block per plane, single barrier)
    hipLaunchKernelGGL(k_winsum, dim3(B * S * C), dim3(256), 0, stream, feats, gsum);
    // Kernel 2: MLP + softmax -> weights
    hipLaunchKernelGGL(k_weights, dim3(B * S * HB), dim3(256), 0, stream,
                       gsum, w1, b1, w2, b2, weights);
    // Kernel 3: weighted fusion (b, c, row-group)
    hipLaunchKernelGGL(k_fuse, dim3(B * C * (H / RPB)), dim3(256), 0, stream,
                       feats, weights, out);
}